// Round 1
// 2979.838 us; speedup vs baseline: 1.0694x; 1.0694x over previous
//
#include <hip/hip_runtime.h>
#include <cstddef>

#define B_  64
#define T_  256
#define I_  256
#define H_  1024
#define C_  1000
#define BH_ (B_ * H_)
#define SLOTS_B_ 24        // ring length for the mid-size workspace tier

typedef _Float16 f16;
typedef __attribute__((ext_vector_type(8))) _Float16 f16x8;
typedef __attribute__((ext_vector_type(4))) float f32x4;

__device__ __forceinline__ float sigmoid_(float v) { return 1.0f / (1.0f + __expf(-v)); }
__device__ __forceinline__ float tanh_(float v) {
  float e = __expf(-2.0f * fabsf(v));
  float t = (1.0f - e) / (1.0f + e);
  return copysignf(t, v);
}

// h store: agent-scope relaxed atomic store -> write-through dword (sc0 sc1).
// Leaves no dirty L2 lines; globally visible at MALL once vmcnt drains at
// __syncthreads. NOTE (R7 lesson): the LOAD side must stay cached -- atomic
// loads are per-lane fabric transactions, ~2.5x total runtime.
__device__ __forceinline__ void storeH2(f16* p, float a, float b) {
  union { f16 h[2]; unsigned u; } pk;
  pk.h[0] = (f16)a; pk.h[1] = (f16)b;
  __hip_atomic_store((unsigned*)p, pk.u, __ATOMIC_RELAXED, __HIP_MEMORY_SCOPE_AGENT);
}

// ---------------- sync protocol (R9 redesign) ----------------
// 4KB sync area, unsigned words, one counter per 128B line:
//   line  0+g : arr0[g] g=0..7  — L0 arrivals (16 blocks/group), monotonic
//   line  8+g : arr1[g]         — L1 arrivals
//   line 16+g : rel0[g]         — broadcast: highest completed L0 phase + 1
//   line 24+g : rel1[g]
// Why: the old two-level barrier had 256 blocks spinning per-lane MALL atomics
// on ONE master line -> its TCC channel serializes ~256 polls per update and
// the release RMWs queue behind the poll storm (multi-us/phase). Here every
// line has <=16 adders or <=32 pollers, and the layers are DECOUPLED: L0 never
// waits on L1 except a lagD-phase WAR/stale bound, so the critical chain is a
// single layer's {drain -> add -> leader detect -> release -> poll}, not a
// global max() over both layers' stragglers each phase.
// Release safety: rel stores issue only after the leader's arr poll returns
// the target (no store speculation); arr adds only after the block's
// __syncthreads vmcnt(0) drain, so rel>=p+1 observed => all phase-p h stores
// visible at MALL. Runahead safety: every block (also on INACTIVE phases)
// gates its arr add on relOwn >= p, so arrival counts can never mix phases.
// Stale-line safety (ring tiers): block re-touches a slot 24 own-phases apart
// and fences every 16 own-phases; cross-block refills of old content complete
// before the filler's release, and lagD<=7 guarantees rel1 >= f-7 at the
// reader's last pre-read fence f => all old fills precede that fence.

__device__ __forceinline__ unsigned ldS(unsigned* p) {
  return __hip_atomic_load(p, __ATOMIC_RELAXED, __HIP_MEMORY_SCOPE_AGENT);
}

__device__ __forceinline__ void waitRel(unsigned* a, unsigned ta,
                                        unsigned* b, unsigned tb) {
  int g = 0;
  for (;;) {
    unsigned va = ldS(a);
    unsigned vb = ldS(b);          // independent loads issue together
    if (va >= ta && vb >= tb) break;
    __builtin_amdgcn_s_sleep(1);
    if (++g > (1 << 17)) break;
  }
}

// One block = 512 threads = 8 waves = (K-split 4) x (N-split 2).
// Block tile: 32 batch rows x 64 gate-cols (4 gates x 16 units).
// Per-wave weights: (K/4) x 32 cols f16 = 128 VGPRs (L1) -> 2 waves/SIMD.
// CRITICAL: prologue loop must be FULLY unrolled so Wreg indexing is static
// (R2's `#pragma unroll 1` demoted Wreg to scratch -> 7 GB/launch re-fetch).
template<bool IS_L1>
__device__ __forceinline__ void role_main(
    const f16* __restrict__ x16,
    const float* __restrict__ Wx, const float* __restrict__ Wh,
    const float* __restrict__ bias,
    f16* __restrict__ h0hist, f16* __restrict__ h1hist,
    unsigned* sync, int bid, int nslots, int fmask, int lagD,
    float* zbAll, float* cLDS, float* biasLDS)
{
  constexpr int KTOT = IS_L1 ? 64 : 40;   // k-tiles of 32 (L0: 8 x-tiles + 32 h-tiles)
  constexpr int NKT  = KTOT / 4;          // per-wave k-tiles (K-split over kq)
  constexpr int KX   = IS_L1 ? 1024 : 256;

  const int tid  = threadIdx.x;
  const int wv   = tid >> 6;          // 0..7
  const int nh   = wv >> 2;           // col-half (32 cols each)
  const int kq   = wv & 3;            // K quarter
  const int lane = tid & 63;
  const int c16  = lane & 15;
  const int quad = lane >> 4;
  const int rr7  = bid & 127;
  const int mgroup  = rr7 & 1;
  const int ubase   = (rr7 >> 1) * 16;
  const int rowbase = mgroup * 32;

  const int  grp       = bid & 7;
  const bool leaderBlk = IS_L1 ? (bid == 128) : (bid == 0);
  unsigned* arrBase = sync + (IS_L1 ?  8 :  0) * 32;
  unsigned* relBase = sync + (IS_L1 ? 24 : 16) * 32;
  unsigned* arrMine = arrBase + grp * 32;
  unsigned* relOwn  = relBase + grp * 32;
  unsigned* relOth  = sync + (IS_L1 ? 16 : 24) * 32 + grp * 32;

  if (tid < 64) biasLDS[tid] = bias[(size_t)(tid >> 4) * H_ + ubase + (tid & 15)];
  cLDS[tid] = 0.0f;

  // ---- weight prologue: global fp32 -> per-wave LDS panel -> f16 B-frags in regs
  f16x8 Wreg[2][NKT];
  {
    f16* zpan = (f16*)zbAll + wv * 1024;   // private 2KB panel per wave
#pragma unroll
    for (int ii = 0; ii < NKT; ++ii) {
      const int kt = kq * NKT + ii;
#pragma unroll
      for (int rw = 0; rw < 16; ++rw) {
        const int krow  = rw * 2 + (lane >> 5);
        const int col32 = lane & 31;
        const int g = nh * 2 + (col32 >> 4);
        const int u = col32 & 15;
        const int k = kt * 32 + krow;
        float wval = (k < KX) ? Wx[((size_t)g * KX + k) * H_ + ubase + u]
                              : Wh[((size_t)g * H_ + (k - KX)) * H_ + ubase + u];
        zpan[krow * 32 + col32] = (f16)wval;
      }
#pragma unroll
      for (int nt = 0; nt < 2; ++nt) {
        f16x8 f;
#pragma unroll
        for (int j = 0; j < 8; ++j)
          f[j] = zpan[(quad * 8 + j) * 32 + nt * 16 + c16];  // B[n=lane&15][k=quad*8+j]
        Wreg[nt][ii] = f;
      }
    }
  }
  __syncthreads();

  const int ktbase = kq * NKT;
  const int row0 = rowbase + c16;

#pragma unroll 1
  for (int p = 0; p <= T_; ++p) {
    const bool active = IS_L1 ? (p >= 1) : (p < T_);
    const int do_fence = (nslots == 2) ? 1
                        : ((fmask < 0) ? 0 : (((p & fmask) == fmask) ? 1 : 0));

    if (tid == 0) {
      // Own-layer gate: relOwn >= p (also blocks arr-counter runahead on the
      // inactive edge phases). Cross-layer gates:
      //   L1 active: needs h0[p-1]            -> rel0 >= p
      //   L0 active (ring tiers): WAR + stale -> rel1 >= p - lagD
      unsigned  tb = 0u;
      unsigned* bp = relOwn;
      if (IS_L1) {
        if (active) { bp = relOth; tb = (unsigned)p; }
      } else if (active && lagD >= 0 && p > lagD) {
        bp = relOth; tb = (unsigned)(p - lagD);
      }
      waitRel(relOwn, (unsigned)p, bp, tb);
      if (do_fence) __builtin_amdgcn_fence(__ATOMIC_ACQUIRE, "agent");
    }
    __syncthreads();

    if (active) {
      // slot map: h0[t] -> slot (t+1)%nslots ; h1[t] -> slot (t+1)%nslots.
      // L0 phase p: reads h0[p-1]=slot p%n, writes h0[p]=slot (p+1)%n.
      // L1 phase p: reads h0[p-1]=slot p%n, h1[p-2]=slot (p-1)%n,
      //             writes h1[p-1]=slot p%n.
      const int sp  = p % nslots;
      const int spm = (p - 1 + nslots) % nslots;
      const int spp = (p + 1) % nslots;
      const f16* __restrict__ hA = h0hist + (size_t)sp * BH_;
      const f16* __restrict__ hB = h1hist + (size_t)spm * BH_;
      f16* __restrict__ hdst = IS_L1 ? (h1hist + (size_t)sp  * BH_)
                                     : (h0hist + (size_t)spp * BH_);

      f16x8 Abuf[6][2];
      auto loadA = [&](int ii, int slot) {
        const int kt = ktbase + ii;
        const int k  = kt * 32 + quad * 8;
#pragma unroll
        for (int mt2 = 0; mt2 < 2; ++mt2) {
          const int row = row0 + mt2 * 16;
          if (!IS_L1 && k < 256) {          // x-part: immutable f16, cached
            Abuf[slot][mt2] = *(const f16x8*)(x16 + ((size_t)row * T_ + p) * I_ + k);
          } else if (IS_L1 && k >= 1024) {
            Abuf[slot][mt2] = *(const f16x8*)(hB + (size_t)row * H_ + (k - 1024));
          } else {
            const int kk = IS_L1 ? k : (k - 256);
            Abuf[slot][mt2] = *(const f16x8*)(hA + (size_t)row * H_ + kk);
          }
        }
      };

      f32x4 acc[2][2];
#pragma unroll
      for (int mt2 = 0; mt2 < 2; ++mt2)
#pragma unroll
        for (int nt = 0; nt < 2; ++nt)
          acc[mt2][nt] = (f32x4)0.0f;

      loadA(0, 0); loadA(1, 1); loadA(2, 2);
      loadA(3, 3); loadA(4, 4); loadA(5, 5);     // prefetch ring depth 6
#pragma unroll
      for (int i = 0; i < NKT; ++i) {
        const int sl = i % 6;
        const f16x8 a0 = Abuf[sl][0];
        const f16x8 a1 = Abuf[sl][1];
        if (i + 6 < NKT) loadA(i + 6, (i + 6) % 6);
        acc[0][0] = __builtin_amdgcn_mfma_f32_16x16x32_f16(a0, Wreg[0][i], acc[0][0], 0, 0, 0);
        acc[0][1] = __builtin_amdgcn_mfma_f32_16x16x32_f16(a0, Wreg[1][i], acc[0][1], 0, 0, 0);
        acc[1][0] = __builtin_amdgcn_mfma_f32_16x16x32_f16(a1, Wreg[0][i], acc[1][0], 0, 0, 0);
        acc[1][1] = __builtin_amdgcn_mfma_f32_16x16x32_f16(a1, Wreg[1][i], acc[1][1], 0, 0, 0);
      }

      // partial z -> LDS; region (nh*4 + kq) so stage-1 sums stride-1024 over kq
      float* zw = zbAll + (nh * 4 + kq) * 1024;
#pragma unroll
      for (int mt2 = 0; mt2 < 2; ++mt2)
#pragma unroll
        for (int nt = 0; nt < 2; ++nt)
#pragma unroll
          for (int e = 0; e < 4; ++e)
            zw[(mt2 * 2 + nt) * 256 + (quad * 4 + e) * 16 + c16] = acc[mt2][nt][e];

      __syncthreads();

      // stage 1: reduce 4 K-partials + bias, in place into kq=0 region
      {
        const int base = tid * 4;          // 512 thr x 4 = 2048 final z
        const int nh1  = base >> 10;
        const int off  = base & 1023;
        f32x4 s = (f32x4)0.0f;
#pragma unroll
        for (int q = 0; q < 4; ++q)
          s += *(const f32x4*)(zbAll + nh1 * 4096 + q * 1024 + off);
        const int nt1 = (off >> 8) & 1;
        const int c0  = off & 15;
        s += *(const f32x4*)(biasLDS + (nh1 * 2 + nt1) * 16 + c0);
        *(f32x4*)(zbAll + nh1 * 4096 + off) = s;
      }
      __syncthreads();

      // stage 2: fused gates; c stays in LDS; h published via write-through 4B stores
      {
        const int row = tid >> 4, u = tid & 15;
        const int mt2 = row >> 4, r16 = row & 15;
        const float z0 = zbAll[0 * 4096 + (mt2 * 2 + 0) * 256 + r16 * 16 + u];
        const float z1 = zbAll[0 * 4096 + (mt2 * 2 + 1) * 256 + r16 * 16 + u];
        const float z2 = zbAll[1 * 4096 + (mt2 * 2 + 0) * 256 + r16 * 16 + u];
        const float z3 = zbAll[1 * 4096 + (mt2 * 2 + 1) * 256 + r16 * 16 + u];
        const float cv = cLDS[tid];
        const float gt = tanh_(z0);
        const float iv = sigmoid_(z1);
        const float fv = sigmoid_(z2);
        const float ov = sigmoid_(z3);
        const float cn = gt * iv + cv * fv;
        cLDS[tid] = cn;
        const float hn = tanh_(cn) * ov;
        const float hn_hi = __shfl_down(hn, 1);
        if ((tid & 1) == 0)
          storeH2(hdst + (size_t)(rowbase + row) * H_ + ubase + u, hn, hn_hi);
      }
    }

    __syncthreads();   // vmcnt(0) drain: write-through h stores visible at MALL
    if (tid == 0) {
      __hip_atomic_fetch_add(arrMine, 1u, __ATOMIC_RELAXED, __HIP_MEMORY_SCOPE_AGENT);
      if (leaderBlk) {
        // single leader per layer: detect 8 group-arrival lines, then
        // broadcast to 8 per-group release lines (<=32 pollers each).
        const unsigned tgt = 16u * (unsigned)(p + 1);
        int gg = 0;
        for (;;) {
          unsigned mn = 0xffffffffu;
#pragma unroll
          for (int j = 0; j < 8; ++j) {
            unsigned v = ldS(arrBase + j * 32);
            mn = (v < mn) ? v : mn;
          }
          if (mn >= tgt) break;
          __builtin_amdgcn_s_sleep(1);
          if (++gg > (1 << 17)) break;
        }
#pragma unroll
        for (int j = 0; j < 8; ++j)
          __hip_atomic_store(relBase + j * 32, (unsigned)(p + 1),
                             __ATOMIC_RELAXED, __HIP_MEMORY_SCOPE_AGENT);
      }
    }
  }
}

__global__ __launch_bounds__(512, 2)
void lstm_persistent(const f16* __restrict__ x16,
                     const float* __restrict__ W0x, const float* __restrict__ W0h, const float* __restrict__ b0,
                     const float* __restrict__ W1x, const float* __restrict__ W1h, const float* __restrict__ b1,
                     f16* h0hist, f16* h1hist, unsigned* sync,
                     int nslots, int fmask, int lagD)
{
  __shared__ float zbAll[8192];    // 32KB: prologue panels / wave partial z / final z
  __shared__ float cLDS[512];
  __shared__ float biasLDS[64];
  const int bid = blockIdx.x;
  if (bid >= 128)
    role_main<true >(x16, W1x, W1h, b1, h0hist, h1hist, sync, bid, nslots, fmask, lagD, zbAll, cLDS, biasLDS);
  else
    role_main<false>(x16, W0x, W0h, b0, h0hist, h1hist, sync, bid, nslots, fmask, lagD, zbAll, cLDS, biasLDS);
}

// x fp32 -> f16, once
__global__ void cvt_x(const float* __restrict__ xin, f16* __restrict__ xo)
{
  const int i = (blockIdx.x * 256 + threadIdx.x) * 8;
  const float4 a = *(const float4*)(xin + i);
  const float4 b = *(const float4*)(xin + i + 4);
  f16x8 v;
  v[0] = (f16)a.x; v[1] = (f16)a.y; v[2] = (f16)a.z; v[3] = (f16)a.w;
  v[4] = (f16)b.x; v[5] = (f16)b.y; v[6] = (f16)b.z; v[7] = (f16)b.w;
  *(f16x8*)(xo + i) = v;
}

// out[b][c] = h1_final[b][:] . Wo[:][c] + bo[c]   (fp32 vector math)
__global__ void out_gemm(const f16* __restrict__ h1,
                         const float* __restrict__ Wo, const float* __restrict__ bo,
                         float* __restrict__ out)
{
  __shared__ float ht[1024][8];
  const int tid = threadIdx.x;    // 128 threads
  const int b0r = blockIdx.y * 4;
  for (int i = tid; i < 4096; i += 128) {
    const int rr = i >> 10, k = i & 1023;
    ht[k][rr] = (float)h1[(size_t)(b0r + rr) * H_ + k];
  }
  __syncthreads();
  const int c = blockIdx.x * 125 + tid;
  if (tid < 125) {
    float a0 = 0.f, a1 = 0.f, a2 = 0.f, a3 = 0.f;
#pragma unroll 4
    for (int k = 0; k < 1024; ++k) {
      const float w = Wo[(size_t)k * C_ + c];
      a0 += ht[k][0] * w;
      a1 += ht[k][1] * w;
      a2 += ht[k][2] * w;
      a3 += ht[k][3] * w;
    }
    const float bb = bo[c];
    out[(size_t)(b0r + 0) * C_ + c] = a0 + bb;
    out[(size_t)(b0r + 1) * C_ + c] = a1 + bb;
    out[(size_t)(b0r + 2) * C_ + c] = a2 + bb;
    out[(size_t)(b0r + 3) * C_ + c] = a3 + bb;
  }
}

extern "C" void kernel_launch(void* const* d_in, const int* in_sizes, int n_in,
                              void* d_out, int out_size, void* d_ws, size_t ws_size,
                              hipStream_t stream)
{
  const float* x   = (const float*)d_in[0];
  const float* W0x = (const float*)d_in[1];
  const float* W0h = (const float*)d_in[2];
  const float* b0  = (const float*)d_in[3];
  const float* W1x = (const float*)d_in[4];
  const float* W1h = (const float*)d_in[5];
  const float* b1  = (const float*)d_in[6];
  const float* Wo  = (const float*)d_in[7];
  const float* bo  = (const float*)d_in[8];

  const size_t slotB = (size_t)BH_ * sizeof(f16);              // 128KB per h slot
  const size_t xB    = (size_t)B_ * T_ * I_ * sizeof(f16);     // 8 MB
  // Tier A: write-once slots for every phase -> no ring reuse, NO fences,
  //         fully decoupled layers (lag bound unnecessary).  ~73 MB.
  // Tier B: 24-slot ring, fence every 16 phases, L0-vs-L1 lag <= 7. ~14 MB.
  // Tier C: 2-slot ring, fence + lockstep-lag every phase (fallback).
  const size_t needA = 4096 + (size_t)2 * (T_ + 1) * slotB + xB;
  const size_t needB = 4096 + (size_t)2 * SLOTS_B_ * slotB + xB;
  int nslots, fmask, lagD;
  if (ws_size >= needA)      { nslots = T_ + 1;   fmask = -1; lagD = -1; }
  else if (ws_size >= needB) { nslots = SLOTS_B_; fmask = 15; lagD = 7;  }
  else                       { nslots = 2;        fmask = 0;  lagD = 0;  }
  const size_t histB = (size_t)nslots * slotB;

  unsigned* sync  = (unsigned*)d_ws;                 // barrier counters (4KB)
  f16* h0hist = (f16*)((char*)d_ws + 4096);
  f16* h1hist = (f16*)((char*)h0hist + histB);
  f16* x16    = (f16*)((char*)h1hist + histB);

  // zero: sync + h0 slot0 (contiguous); h1 slot0
  hipMemsetAsync(d_ws, 0, 4096 + slotB, stream);
  hipMemsetAsync(h1hist, 0, slotB, stream);

  hipLaunchKernelGGL(cvt_x, dim3((B_ * T_ * I_) / (256 * 8)), dim3(256), 0, stream, x, x16);

  hipLaunchKernelGGL(lstm_persistent, dim3(256), dim3(512), 0, stream,
                     x16, W0x, W0h, b0, W1x, W1h, b1, h0hist, h1hist, sync,
                     nslots, fmask, lagD);

  // final h1 = timestep T-1 -> written at phase T -> slot T % nslots
  f16* h1fin = h1hist + (size_t)(T_ % nslots) * BH_;
  hipLaunchKernelGGL(out_gemm, dim3(8, 16), dim3(128), 0, stream,
                     h1fin, Wo, bo, (float*)d_out);
}

// Round 2
// 2541.934 us; speedup vs baseline: 1.2536x; 1.1723x over previous
//
#include <hip/hip_runtime.h>
#include <cstddef>

#define B_  64
#define T_  256
#define I_  256
#define H_  1024
#define C_  1000
#define BH_ (B_ * H_)
#define SLOTS_B_ 24        // ring length for the mid-size workspace tier

typedef _Float16 f16;
typedef __attribute__((ext_vector_type(8))) _Float16 f16x8;
typedef __attribute__((ext_vector_type(4))) float f32x4;

__device__ __forceinline__ float sigmoid_(float v) { return 1.0f / (1.0f + __expf(-v)); }
__device__ __forceinline__ float tanh_(float v) {
  float e = __expf(-2.0f * fabsf(v));
  float t = (1.0f - e) / (1.0f + e);
  return copysignf(t, v);
}

// h store: agent-scope relaxed atomic store -> write-through dword.
// Leaves no dirty L2 lines; globally visible at MALL once vmcnt drains at
// __syncthreads. Load side stays cached (R7 lesson: atomic loads = per-lane
// fabric transactions, ~2.5x runtime).
__device__ __forceinline__ void storeH2(f16* p, float a, float b) {
  union { f16 h[2]; unsigned u; } pk;
  pk.h[0] = (f16)a; pk.h[1] = (f16)b;
  __hip_atomic_store((unsigned*)p, pk.u, __ATOMIC_RELAXED, __HIP_MEMORY_SCOPE_AGENT);
}

// ---------------- sync protocol (R2 redesign: leaderless) ----------------
// Evidence: R0 (2-level barrier) ~= R1 (leader+release) at ~10.7us/phase ->
// the cost is SERIAL MALL HOPS (5 per phase), not poll contention. This
// version cuts the chain to 3 hops: {drain h stores} -> {arrival add} ->
// {consumer observes min over 8 arrival counters}.
//
// 4 closures of 64 blocks: C(layer,mgroup). h0[rows of mgroup m] is produced
// and consumed only within closure column m. Each closure has 8 counters
// (one 128B line each, 8 adder-blocks per counter), at
//   sync + ((layer*2+m)*8 + sub)*32,  sub = (ubase_index & 7).
// Blocks add +1 (agent RMW) per phase AFTER the __syncthreads vmcnt(0) drain
// of their write-through h stores => counter >= 8p observed implies all that
// closure's phase-(p-1) h stores are visible at MALL.
// Soundness of min-gating (induction on p): the first block entering phase p
// sees its own closure's counters all >= 8p while no count exceeds p, forcing
// every block's count == p, i.e. all completed p-1. Gates:
//   L0 phase p: C0m >= 8p  (+ ring tiers: C1m >= 8(p-lagD) WAR/stale bound)
//   L1 phase p: C0m >= 8p before h0 k-tiles (pre-satisfied in tier A since
//               L0 runs ahead); C1m >= 8p only before h1 k-tiles -> half of
//               L1's GEMM overlaps its own-recurrence wait.
// Inactive edge phases skip gates but still add, keeping counters aligned.

__device__ __forceinline__ unsigned ldS(unsigned* p) {
  return __hip_atomic_load(p, __ATOMIC_RELAXED, __HIP_MEMORY_SCOPE_AGENT);
}

__device__ __forceinline__ void waitCtr8(unsigned* base, unsigned tgt) {
  int g = 0;
  for (;;) {
    unsigned mn = 0xffffffffu;
#pragma unroll
    for (int j = 0; j < 8; ++j) {
      unsigned v = ldS(base + j * 32);
      mn = (v < mn) ? v : mn;
    }
    if (mn >= tgt) break;
    __builtin_amdgcn_s_sleep(1);
    if (++g > (1 << 17)) break;
  }
}

// One block = 512 threads = 8 waves = (K-split 4) x (N-split 2).
// Block tile: 32 batch rows x 64 gate-cols (4 gates x 16 units).
// k-tile map (per wave kq):
//   L0: ii<2 -> x-tile kq*2+ii (k<256, immutable -> computed PRE-gate);
//       ii>=2 -> h0-tile kq*8+(ii-2)
//   L1: ii<8 -> h0-tile kq*8+ii (gated on C0m, pre-satisfied);
//       ii>=8 -> h1-tile kq*8+(ii-8) (gated on C1m - the critical gate)
// CRITICAL: prologue loop must stay FULLY unrolled so Wreg indexing is static
// (R2-history lesson: `#pragma unroll 1` demoted Wreg to scratch -> 7 GB refetch).
template<bool IS_L1>
__device__ __forceinline__ void role_main(
    const f16* __restrict__ x16,
    const float* __restrict__ Wx, const float* __restrict__ Wh,
    const float* __restrict__ bias,
    f16* __restrict__ h0hist, f16* __restrict__ h1hist,
    unsigned* sync, int bid, int nslots, int fmask, int lagD,
    float* zbAll, float* cLDS, float* biasLDS)
{
  constexpr int NKT = IS_L1 ? 16 : 10;    // k-tiles of 32 per wave
  constexpr int KX  = IS_L1 ? 1024 : 256; // Wx/Wh k boundary

  const int tid  = threadIdx.x;
  const int wv   = tid >> 6;          // 0..7
  const int nh   = wv >> 2;           // col-half (32 cols each)
  const int kq   = wv & 3;            // K quarter
  const int lane = tid & 63;
  const int c16  = lane & 15;
  const int quad = lane >> 4;
  const int rr7  = bid & 127;
  const int mgroup  = rr7 & 1;
  const int ubase   = (rr7 >> 1) * 16;
  const int rowbase = mgroup * 32;

  const int sub = (rr7 >> 1) & 7;
  unsigned* ctrC0 = sync + ((0 * 2 + mgroup) * 8) * 32;
  unsigned* ctrC1 = sync + ((1 * 2 + mgroup) * 8) * 32;
  unsigned* ctrOwn = IS_L1 ? ctrC1 : ctrC0;
  unsigned* arrLine = ctrOwn + sub * 32;

  // per-wave tile -> global-k base
  auto kmap = [&](int ii) -> int {
    if (!IS_L1) return (ii < 2) ? (kq * 2 + ii) * 32 : 256 + (kq * 8 + (ii - 2)) * 32;
    else        return (ii < 8) ? (kq * 8 + ii) * 32 : 1024 + (kq * 8 + (ii - 8)) * 32;
  };

  if (tid < 64) biasLDS[tid] = bias[(size_t)(tid >> 4) * H_ + ubase + (tid & 15)];
  cLDS[tid] = 0.0f;

  // ---- weight prologue: global fp32 -> per-wave LDS panel -> f16 B-frags in regs
  f16x8 Wreg[2][NKT];
  {
    f16* zpan = (f16*)zbAll + wv * 1024;   // private 2KB panel per wave
#pragma unroll
    for (int ii = 0; ii < NKT; ++ii) {
      const int kbase = kmap(ii);
#pragma unroll
      for (int rw = 0; rw < 16; ++rw) {
        const int krow  = rw * 2 + (lane >> 5);
        const int col32 = lane & 31;
        const int g = nh * 2 + (col32 >> 4);
        const int u = col32 & 15;
        const int k = kbase + krow;
        float wval = (k < KX) ? Wx[((size_t)g * KX + k) * H_ + ubase + u]
                              : Wh[((size_t)g * H_ + (k - KX)) * H_ + ubase + u];
        zpan[krow * 32 + col32] = (f16)wval;
      }
#pragma unroll
      for (int nt = 0; nt < 2; ++nt) {
        f16x8 f;
#pragma unroll
        for (int j = 0; j < 8; ++j)
          f[j] = zpan[(quad * 8 + j) * 32 + nt * 16 + c16];  // B[n=lane&15][k=quad*8+j]
        Wreg[nt][ii] = f;
      }
    }
  }
  __syncthreads();

  const int row0 = rowbase + c16;

#pragma unroll 1
  for (int p = 0; p <= T_; ++p) {
    const bool active = IS_L1 ? (p >= 1) : (p < T_);
    const int do_fence = (nslots == 2) ? 1
                        : ((fmask < 0) ? 0 : (((p & fmask) == fmask) ? 1 : 0));

    if (active) {
      // slot map: h0[t] -> slot (t+1)%nslots ; h1[t] -> slot (t+1)%nslots.
      // L0 phase p: reads h0[p-1]=slot p%n, writes h0[p]=slot (p+1)%n.
      // L1 phase p: reads h0[p-1]=slot p%n, h1[p-2]=slot (p-1)%n,
      //             writes h1[p-1]=slot p%n.
      const int sp  = p % nslots;
      const int spm = (p - 1 + nslots) % nslots;
      const int spp = (p + 1) % nslots;
      const f16* __restrict__ hA = h0hist + (size_t)sp * BH_;
      const f16* __restrict__ hB = h1hist + (size_t)spm * BH_;
      f16* __restrict__ hdst = IS_L1 ? (h1hist + (size_t)sp  * BH_)
                                     : (h0hist + (size_t)spp * BH_);

      f16x8 Abuf[8][2];
      auto loadTile = [&](int ii, int slot) {
        const int kb = kmap(ii) + quad * 8;
#pragma unroll
        for (int mt2 = 0; mt2 < 2; ++mt2) {
          const int row = row0 + mt2 * 16;
          const f16* src;
          if (!IS_L1) {
            src = (ii < 2) ? (x16 + ((size_t)row * T_ + p) * I_ + kb)
                           : (hA + (size_t)row * H_ + (kb - 256));
          } else {
            src = (ii < 8) ? (hA + (size_t)row * H_ + kb)
                           : (hB + (size_t)row * H_ + (kb - 1024));
          }
          Abuf[slot][mt2] = *(const f16x8*)src;
        }
      };

      f32x4 acc[2][2];
#pragma unroll
      for (int mt2 = 0; mt2 < 2; ++mt2)
#pragma unroll
        for (int nt = 0; nt < 2; ++nt)
          acc[mt2][nt] = (f32x4)0.0f;

      auto mfma4 = [&](int slot, int ii) {
        const f16x8 a0 = Abuf[slot][0];
        const f16x8 a1 = Abuf[slot][1];
        acc[0][0] = __builtin_amdgcn_mfma_f32_16x16x32_f16(a0, Wreg[0][ii], acc[0][0], 0, 0, 0);
        acc[0][1] = __builtin_amdgcn_mfma_f32_16x16x32_f16(a0, Wreg[1][ii], acc[0][1], 0, 0, 0);
        acc[1][0] = __builtin_amdgcn_mfma_f32_16x16x32_f16(a1, Wreg[0][ii], acc[1][0], 0, 0, 0);
        acc[1][1] = __builtin_amdgcn_mfma_f32_16x16x32_f16(a1, Wreg[1][ii], acc[1][1], 0, 0, 0);
      };

      if (!IS_L1) {
        // ---- pre-gate x-part (immutable input, off the critical chain)
        loadTile(0, 0); loadTile(1, 1);
        mfma4(0, 0); mfma4(1, 1);
        // ---- gate: own closure C0m; ring tiers add the WAR/stale lag bound
        if (tid == 0) {
          waitCtr8(ctrC0, 8u * (unsigned)p);
          if (lagD >= 0 && p > lagD) waitCtr8(ctrC1, 8u * (unsigned)(p - lagD));
          if (do_fence) __builtin_amdgcn_fence(__ATOMIC_ACQUIRE, "agent");
        }
        __syncthreads();
        // ---- h-part: issue ALL loads, then MFMA (one MALL RT, not three)
#pragma unroll
        for (int ii = 2; ii < 10; ++ii) loadTile(ii, ii - 2);
#pragma unroll
        for (int ii = 2; ii < 10; ++ii) mfma4(ii - 2, ii);
      } else {
        // ---- gate 1: h0[p-1] ready (pre-satisfied in tier A: L0 runs ahead)
        if (tid == 0) {
          waitCtr8(ctrC0, 8u * (unsigned)p);
          if (do_fence) __builtin_amdgcn_fence(__ATOMIC_ACQUIRE, "agent");
        }
        __syncthreads();
#pragma unroll
        for (int ii = 0; ii < 8; ++ii) loadTile(ii, ii);
#pragma unroll
        for (int ii = 0; ii < 8; ++ii) mfma4(ii, ii);
        // ---- gate 2: own recurrence h1[p-2] (the critical gate; half the
        //      GEMM above overlaps this wait chain)
        if (tid == 0) {
          waitCtr8(ctrC1, 8u * (unsigned)p);
          if (do_fence) __builtin_amdgcn_fence(__ATOMIC_ACQUIRE, "agent");
        }
        __syncthreads();
#pragma unroll
        for (int ii = 8; ii < 16; ++ii) loadTile(ii, ii - 8);
#pragma unroll
        for (int ii = 8; ii < 16; ++ii) mfma4(ii - 8, ii);
      }

      // partial z -> LDS; region (nh*4 + kq) so stage-1 sums stride-1024 over kq
      float* zw = zbAll + (nh * 4 + kq) * 1024;
#pragma unroll
      for (int mt2 = 0; mt2 < 2; ++mt2)
#pragma unroll
        for (int nt = 0; nt < 2; ++nt)
#pragma unroll
          for (int e = 0; e < 4; ++e)
            zw[(mt2 * 2 + nt) * 256 + (quad * 4 + e) * 16 + c16] = acc[mt2][nt][e];

      __syncthreads();

      // stage 1: reduce 4 K-partials + bias, in place into kq=0 region
      {
        const int base = tid * 4;          // 512 thr x 4 = 2048 final z
        const int nh1  = base >> 10;
        const int off  = base & 1023;
        f32x4 s = (f32x4)0.0f;
#pragma unroll
        for (int q = 0; q < 4; ++q)
          s += *(const f32x4*)(zbAll + nh1 * 4096 + q * 1024 + off);
        const int nt1 = (off >> 8) & 1;
        const int c0  = off & 15;
        s += *(const f32x4*)(biasLDS + (nh1 * 2 + nt1) * 16 + c0);
        *(f32x4*)(zbAll + nh1 * 4096 + off) = s;
      }
      __syncthreads();

      // stage 2: fused gates; c stays in LDS; h published via write-through 4B stores
      {
        const int row = tid >> 4, u = tid & 15;
        const int mt2 = row >> 4, r16 = row & 15;
        const float z0 = zbAll[0 * 4096 + (mt2 * 2 + 0) * 256 + r16 * 16 + u];
        const float z1 = zbAll[0 * 4096 + (mt2 * 2 + 1) * 256 + r16 * 16 + u];
        const float z2 = zbAll[1 * 4096 + (mt2 * 2 + 0) * 256 + r16 * 16 + u];
        const float z3 = zbAll[1 * 4096 + (mt2 * 2 + 1) * 256 + r16 * 16 + u];
        const float cv = cLDS[tid];
        const float gt = tanh_(z0);
        const float iv = sigmoid_(z1);
        const float fv = sigmoid_(z2);
        const float ov = sigmoid_(z3);
        const float cn = gt * iv + cv * fv;
        cLDS[tid] = cn;
        const float hn = tanh_(cn) * ov;
        const float hn_hi = __shfl_down(hn, 1);
        if ((tid & 1) == 0)
          storeH2(hdst + (size_t)(rowbase + row) * H_ + ubase + u, hn, hn_hi);
      }
    }

    __syncthreads();   // vmcnt(0) drain: write-through h stores visible at MALL
    if (tid == 0)
      __hip_atomic_fetch_add(arrLine, 1u, __ATOMIC_RELAXED, __HIP_MEMORY_SCOPE_AGENT);
  }
}

__global__ __launch_bounds__(512, 2)
void lstm_persistent(const f16* __restrict__ x16,
                     const float* __restrict__ W0x, const float* __restrict__ W0h, const float* __restrict__ b0,
                     const float* __restrict__ W1x, const float* __restrict__ W1h, const float* __restrict__ b1,
                     f16* h0hist, f16* h1hist, unsigned* sync,
                     int nslots, int fmask, int lagD)
{
  __shared__ float zbAll[8192];    // 32KB: prologue panels / wave partial z / final z
  __shared__ float cLDS[512];
  __shared__ float biasLDS[64];
  const int bid = blockIdx.x;
  if (bid >= 128)
    role_main<true >(x16, W1x, W1h, b1, h0hist, h1hist, sync, bid, nslots, fmask, lagD, zbAll, cLDS, biasLDS);
  else
    role_main<false>(x16, W0x, W0h, b0, h0hist, h1hist, sync, bid, nslots, fmask, lagD, zbAll, cLDS, biasLDS);
}

// x fp32 -> f16, once
__global__ void cvt_x(const float* __restrict__ xin, f16* __restrict__ xo)
{
  const int i = (blockIdx.x * 256 + threadIdx.x) * 8;
  const float4 a = *(const float4*)(xin + i);
  const float4 b = *(const float4*)(xin + i + 4);
  f16x8 v;
  v[0] = (f16)a.x; v[1] = (f16)a.y; v[2] = (f16)a.z; v[3] = (f16)a.w;
  v[4] = (f16)b.x; v[5] = (f16)b.y; v[6] = (f16)b.z; v[7] = (f16)b.w;
  *(f16x8*)(xo + i) = v;
}

// out[b][c] = h1_final[b][:] . Wo[:][c] + bo[c]   (fp32 vector math)
__global__ void out_gemm(const f16* __restrict__ h1,
                         const float* __restrict__ Wo, const float* __restrict__ bo,
                         float* __restrict__ out)
{
  __shared__ float ht[1024][8];
  const int tid = threadIdx.x;    // 128 threads
  const int b0r = blockIdx.y * 4;
  for (int i = tid; i < 4096; i += 128) {
    const int rr = i >> 10, k = i & 1023;
    ht[k][rr] = (float)h1[(size_t)(b0r + rr) * H_ + k];
  }
  __syncthreads();
  const int c = blockIdx.x * 125 + tid;
  if (tid < 125) {
    float a0 = 0.f, a1 = 0.f, a2 = 0.f, a3 = 0.f;
#pragma unroll 4
    for (int k = 0; k < 1024; ++k) {
      const float w = Wo[(size_t)k * C_ + c];
      a0 += ht[k][0] * w;
      a1 += ht[k][1] * w;
      a2 += ht[k][2] * w;
      a3 += ht[k][3] * w;
    }
    const float bb = bo[c];
    out[(size_t)(b0r + 0) * C_ + c] = a0 + bb;
    out[(size_t)(b0r + 1) * C_ + c] = a1 + bb;
    out[(size_t)(b0r + 2) * C_ + c] = a2 + bb;
    out[(size_t)(b0r + 3) * C_ + c] = a3 + bb;
  }
}

extern "C" void kernel_launch(void* const* d_in, const int* in_sizes, int n_in,
                              void* d_out, int out_size, void* d_ws, size_t ws_size,
                              hipStream_t stream)
{
  const float* x   = (const float*)d_in[0];
  const float* W0x = (const float*)d_in[1];
  const float* W0h = (const float*)d_in[2];
  const float* b0  = (const float*)d_in[3];
  const float* W1x = (const float*)d_in[4];
  const float* W1h = (const float*)d_in[5];
  const float* b1  = (const float*)d_in[6];
  const float* Wo  = (const float*)d_in[7];
  const float* bo  = (const float*)d_in[8];

  const size_t slotB = (size_t)BH_ * sizeof(f16);              // 128KB per h slot
  const size_t xB    = (size_t)B_ * T_ * I_ * sizeof(f16);     // 8 MB
  // Tier A: write-once slots for every phase -> no ring reuse, NO fences,
  //         fully decoupled layers (lag bound unnecessary).  ~73 MB.
  // Tier B: 24-slot ring, fence every 16 phases, L0-vs-L1 lag <= 7. ~14 MB.
  // Tier C: 2-slot ring, fence + lockstep-lag every phase (fallback).
  const size_t needA = 4096 + (size_t)2 * (T_ + 1) * slotB + xB;
  const size_t needB = 4096 + (size_t)2 * SLOTS_B_ * slotB + xB;
  int nslots, fmask, lagD;
  if (ws_size >= needA)      { nslots = T_ + 1;   fmask = -1; lagD = -1; }
  else if (ws_size >= needB) { nslots = SLOTS_B_; fmask = 15; lagD = 7;  }
  else                       { nslots = 2;        fmask = 0;  lagD = 0;  }
  const size_t histB = (size_t)nslots * slotB;

  unsigned* sync  = (unsigned*)d_ws;                 // arrival counters (4KB)
  f16* h0hist = (f16*)((char*)d_ws + 4096);
  f16* h1hist = (f16*)((char*)h0hist + histB);
  f16* x16    = (f16*)((char*)h1hist + histB);

  // zero: sync + h0 slot0 (contiguous); h1 slot0
  hipMemsetAsync(d_ws, 0, 4096 + slotB, stream);
  hipMemsetAsync(h1hist, 0, slotB, stream);

  hipLaunchKernelGGL(cvt_x, dim3((B_ * T_ * I_) / (256 * 8)), dim3(256), 0, stream, x, x16);

  hipLaunchKernelGGL(lstm_persistent, dim3(256), dim3(512), 0, stream,
                     x16, W0x, W0h, b0, W1x, W1h, b1, h0hist, h1hist, sync,
                     nslots, fmask, lagD);

  // final h1 = timestep T-1 -> written at phase T -> slot T % nslots
  f16* h1fin = h1hist + (size_t)(T_ % nslots) * BH_;
  hipLaunchKernelGGL(out_gemm, dim3(8, 16), dim3(128), 0, stream,
                     h1fin, Wo, bo, (float*)d_out);
}

// Round 4
// 2529.414 us; speedup vs baseline: 1.2599x; 1.0049x over previous
//
#include <hip/hip_runtime.h>
#include <cstddef>

#define B_  64
#define T_  256
#define I_  256
#define H_  1024
#define C_  1000
#define BH_ (B_ * H_)
#define SLOTS_B_ 24        // ring length for the mid-size workspace tier

typedef _Float16 f16;
typedef __attribute__((ext_vector_type(8))) _Float16 f16x8;
typedef __attribute__((ext_vector_type(4))) float f32x4;

__device__ __forceinline__ float sigmoid_(float v) { return 1.0f / (1.0f + __expf(-v)); }
__device__ __forceinline__ float tanh_(float v) {
  float e = __expf(-2.0f * fabsf(v));
  float t = (1.0f - e) / (1.0f + e);
  return copysignf(t, v);
}

// h store: agent-scope relaxed atomic store -> write-through dword.
__device__ __forceinline__ void storeH2(f16* p, float a, float b) {
  union { f16 h[2]; unsigned u; } pk;
  pk.h[0] = (f16)a; pk.h[1] = (f16)b;
  __hip_atomic_store((unsigned*)p, pk.u, __ATOMIC_RELAXED, __HIP_MEMORY_SCOPE_AGENT);
}

// ---------------- sync protocol (R2 leaderless; R3 adds timing+backoff) ----
// 4 closures of 64 blocks: C(layer,mgroup); 8 arrival counters each (128B
// lines), 8 adder-blocks per counter. Gate = min over own closure's 8
// counters >= 8p. See R2 notes for the soundness induction.
// R3: waitCtr8 returns 100MHz-ticks spent waiting (s_memrealtime; DVFS-
// immune) and backs off s_sleep 1->8 to cut poll pressure on the MALL lines.
// NOTE: s_sleep arg must be a LITERAL -> constant-dispatch switch.

__device__ __forceinline__ unsigned ldS(unsigned* p) {
  return __hip_atomic_load(p, __ATOMIC_RELAXED, __HIP_MEMORY_SCOPE_AGENT);
}

__device__ __forceinline__ void sleepN(int lvl) {
  switch (lvl) {
    case 0: __builtin_amdgcn_s_sleep(1); break;
    case 1: __builtin_amdgcn_s_sleep(2); break;
    case 2: __builtin_amdgcn_s_sleep(4); break;
    default: __builtin_amdgcn_s_sleep(8); break;
  }
}

__device__ __forceinline__ long long waitCtr8(unsigned* base, unsigned tgt) {
  unsigned mn = 0xffffffffu;
#pragma unroll
  for (int j = 0; j < 8; ++j) {
    unsigned v = ldS(base + j * 32);
    mn = (v < mn) ? v : mn;
  }
  if (mn >= tgt) return 0;                       // fast path: no wait
  const long long t0 = __builtin_amdgcn_s_memrealtime();
  int lvl = 0, g = 0;
  for (;;) {
    mn = 0xffffffffu;
#pragma unroll
    for (int j = 0; j < 8; ++j) {
      unsigned v = ldS(base + j * 32);
      mn = (v < mn) ? v : mn;
    }
    if (mn >= tgt) break;
    sleepN(lvl);
    if (lvl < 3) ++lvl;                          // 64..512cy backoff
    if (++g > (1 << 17)) break;
  }
  return __builtin_amdgcn_s_memrealtime() - t0;
}

// One block = 512 threads = 8 waves = (K-split 4) x (N-split 2).
// Block tile: 32 batch rows x 64 gate-cols. See R2 notes for k-tile map.
// CRITICAL: prologue loop must stay FULLY unrolled so Wreg indexing is static.
template<bool IS_L1>
__device__ __forceinline__ void role_main(
    const f16* __restrict__ x16, const float* __restrict__ x32,
    const float* __restrict__ Wx, const float* __restrict__ Wh,
    const float* __restrict__ bias,
    f16* __restrict__ h0hist, f16* __restrict__ h1hist,
    unsigned* sync, int bid, int nslots, int fmask, int lagD,
    float* zbAll, float* cLDS, float* biasLDS)
{
  constexpr int NKT = IS_L1 ? 16 : 10;    // k-tiles of 32 per wave
  constexpr int KX  = IS_L1 ? 1024 : 256; // Wx/Wh k boundary

  const int tid  = threadIdx.x;
  const int wv   = tid >> 6;          // 0..7
  const int nh   = wv >> 2;           // col-half (32 cols each)
  const int kq   = wv & 3;            // K quarter
  const int lane = tid & 63;
  const int c16  = lane & 15;
  const int quad = lane >> 4;
  const int rr7  = bid & 127;
  const int mgroup  = rr7 & 1;
  const int ubase   = (rr7 >> 1) * 16;
  const int rowbase = mgroup * 32;

  const int sub = (rr7 >> 1) & 7;
  unsigned* ctrC0 = sync + ((0 * 2 + mgroup) * 8) * 32;
  unsigned* ctrC1 = sync + ((1 * 2 + mgroup) * 8) * 32;
  unsigned* ctrOwn = IS_L1 ? ctrC1 : ctrC0;
  unsigned* arrLine = ctrOwn + sub * 32;

  auto kmap = [&](int ii) -> int {
    if (!IS_L1) return (ii < 2) ? (kq * 2 + ii) * 32 : 256 + (kq * 8 + (ii - 2)) * 32;
    else        return (ii < 8) ? (kq * 8 + ii) * 32 : 1024 + (kq * 8 + (ii - 8)) * 32;
  };

  if (tid < 64) biasLDS[tid] = bias[(size_t)(tid >> 4) * H_ + ubase + (tid & 15)];
  cLDS[tid] = 0.0f;

  // ---- weight prologue: global fp32 -> per-wave LDS panel -> f16 B-frags
  f16x8 Wreg[2][NKT];
  {
    f16* zpan = (f16*)zbAll + wv * 1024;
#pragma unroll
    for (int ii = 0; ii < NKT; ++ii) {
      const int kbase = kmap(ii);
#pragma unroll
      for (int rw = 0; rw < 16; ++rw) {
        const int krow  = rw * 2 + (lane >> 5);
        const int col32 = lane & 31;
        const int g = nh * 2 + (col32 >> 4);
        const int u = col32 & 15;
        const int k = kbase + krow;
        float wval = (k < KX) ? Wx[((size_t)g * KX + k) * H_ + ubase + u]
                              : Wh[((size_t)g * H_ + (k - KX)) * H_ + ubase + u];
        zpan[krow * 32 + col32] = (f16)wval;
      }
#pragma unroll
      for (int nt = 0; nt < 2; ++nt) {
        f16x8 f;
#pragma unroll
        for (int j = 0; j < 8; ++j)
          f[j] = zpan[(quad * 8 + j) * 32 + nt * 16 + c16];
        Wreg[nt][ii] = f;
      }
    }
  }
  __syncthreads();

  const int row0 = rowbase + c16;
  long long wsum = 0;                 // accumulated gate-wait (100MHz ticks)

#pragma unroll 1
  for (int p = 0; p <= T_; ++p) {
    const bool active = IS_L1 ? (p >= 1) : (p < T_);
    const int do_fence = (nslots == 2) ? 1
                        : ((fmask < 0) ? 0 : (((p & fmask) == fmask) ? 1 : 0));

    if (active) {
      const int sp  = p % nslots;
      const int spm = (p - 1 + nslots) % nslots;
      const int spp = (p + 1) % nslots;
      const f16* __restrict__ hA = h0hist + (size_t)sp * BH_;
      const f16* __restrict__ hB = h1hist + (size_t)spm * BH_;
      f16* __restrict__ hdst = IS_L1 ? (h1hist + (size_t)sp  * BH_)
                                     : (h0hist + (size_t)spp * BH_);

      f16x8 Abuf[8][2];
      auto loadTile = [&](int ii, int slot) {
        const int kb = kmap(ii) + quad * 8;
#pragma unroll
        for (int mt2 = 0; mt2 < 2; ++mt2) {
          const int row = row0 + mt2 * 16;
          const f16* src;
          if (!IS_L1) {
            src = (ii < 2) ? (x16 + ((size_t)row * T_ + p) * I_ + kb)
                           : (hA + (size_t)row * H_ + (kb - 256));
          } else {
            src = (ii < 8) ? (hA + (size_t)row * H_ + kb)
                           : (hB + (size_t)row * H_ + (kb - 1024));
          }
          Abuf[slot][mt2] = *(const f16x8*)src;
        }
      };

      f32x4 acc[2][2];
#pragma unroll
      for (int mt2 = 0; mt2 < 2; ++mt2)
#pragma unroll
        for (int nt = 0; nt < 2; ++nt)
          acc[mt2][nt] = (f32x4)0.0f;

      auto mfma4 = [&](int slot, int ii) {
        const f16x8 a0 = Abuf[slot][0];
        const f16x8 a1 = Abuf[slot][1];
        acc[0][0] = __builtin_amdgcn_mfma_f32_16x16x32_f16(a0, Wreg[0][ii], acc[0][0], 0, 0, 0);
        acc[0][1] = __builtin_amdgcn_mfma_f32_16x16x32_f16(a0, Wreg[1][ii], acc[0][1], 0, 0, 0);
        acc[1][0] = __builtin_amdgcn_mfma_f32_16x16x32_f16(a1, Wreg[0][ii], acc[1][0], 0, 0, 0);
        acc[1][1] = __builtin_amdgcn_mfma_f32_16x16x32_f16(a1, Wreg[1][ii], acc[1][1], 0, 0, 0);
      };

      if (!IS_L1) {
        loadTile(0, 0); loadTile(1, 1);        // pre-gate x-part
        mfma4(0, 0); mfma4(1, 1);
        if (tid == 0) {
          wsum += waitCtr8(ctrC0, 8u * (unsigned)p);
          if (lagD >= 0 && p > lagD) wsum += waitCtr8(ctrC1, 8u * (unsigned)(p - lagD));
          if (do_fence) __builtin_amdgcn_fence(__ATOMIC_ACQUIRE, "agent");
        }
        __syncthreads();
#pragma unroll
        for (int ii = 2; ii < 10; ++ii) loadTile(ii, ii - 2);
#pragma unroll
        for (int ii = 2; ii < 10; ++ii) mfma4(ii - 2, ii);
      } else {
        if (tid == 0) {
          wsum += waitCtr8(ctrC0, 8u * (unsigned)p);   // gate1 (h0 ready)
          if (do_fence) __builtin_amdgcn_fence(__ATOMIC_ACQUIRE, "agent");
        }
        __syncthreads();
#pragma unroll
        for (int ii = 0; ii < 8; ++ii) loadTile(ii, ii);
#pragma unroll
        for (int ii = 0; ii < 8; ++ii) mfma4(ii, ii);
        if (tid == 0) {
          wsum += waitCtr8(ctrC1, 8u * (unsigned)p);   // gate2 (own recurrence)
          if (do_fence) __builtin_amdgcn_fence(__ATOMIC_ACQUIRE, "agent");
        }
        __syncthreads();
#pragma unroll
        for (int ii = 8; ii < 16; ++ii) loadTile(ii, ii - 8);
#pragma unroll
        for (int ii = 8; ii < 16; ++ii) mfma4(ii - 8, ii);
      }

      float* zw = zbAll + (nh * 4 + kq) * 1024;
#pragma unroll
      for (int mt2 = 0; mt2 < 2; ++mt2)
#pragma unroll
        for (int nt = 0; nt < 2; ++nt)
#pragma unroll
          for (int e = 0; e < 4; ++e)
            zw[(mt2 * 2 + nt) * 256 + (quad * 4 + e) * 16 + c16] = acc[mt2][nt][e];

      __syncthreads();

      {
        const int base = tid * 4;
        const int nh1  = base >> 10;
        const int off  = base & 1023;
        f32x4 s = (f32x4)0.0f;
#pragma unroll
        for (int q = 0; q < 4; ++q)
          s += *(const f32x4*)(zbAll + nh1 * 4096 + q * 1024 + off);
        const int nt1 = (off >> 8) & 1;
        const int c0  = off & 15;
        s += *(const f32x4*)(biasLDS + (nh1 * 2 + nt1) * 16 + c0);
        *(f32x4*)(zbAll + nh1 * 4096 + off) = s;
      }
      __syncthreads();

      {
        const int row = tid >> 4, u = tid & 15;
        const int mt2 = row >> 4, r16 = row & 15;
        const float z0 = zbAll[0 * 4096 + (mt2 * 2 + 0) * 256 + r16 * 16 + u];
        const float z1 = zbAll[0 * 4096 + (mt2 * 2 + 1) * 256 + r16 * 16 + u];
        const float z2 = zbAll[1 * 4096 + (mt2 * 2 + 0) * 256 + r16 * 16 + u];
        const float z3 = zbAll[1 * 4096 + (mt2 * 2 + 1) * 256 + r16 * 16 + u];
        const float cv = cLDS[tid];
        const float gt = tanh_(z0);
        const float iv = sigmoid_(z1);
        const float fv = sigmoid_(z2);
        const float ov = sigmoid_(z3);
        const float cn = gt * iv + cv * fv;
        cLDS[tid] = cn;
        const float hn = tanh_(cn) * ov;
        const float hn_hi = __shfl_down(hn, 1);
        if ((tid & 1) == 0)
          storeH2(hdst + (size_t)(rowbase + row) * H_ + ubase + u, hn, hn_hi);
      }
    }

    __syncthreads();   // vmcnt(0) drain: h stores visible at MALL
    if (tid == 0)
      __hip_atomic_fetch_add(arrLine, 1u, __ATOMIC_RELAXED, __HIP_MEMORY_SCOPE_AGENT);
  }

  // ---- R3 instrumentation export (counter side-channels) ----
  // WRITE channel <- block 0 (L0 gate-wait): nlines = ticks/2 distinct 128B
  //   lines get a 4B write-through store (32B each in WRITE_SIZE).
  //   L0_wait_ms = dWRITE_MB * 0.625.  Saturates at 4ms.
  // FETCH channel <- block 128 (L1 gate1+gate2 wait): nlines = ticks/2
  //   distinct 128B lines read from long-evicted fp32 x.
  //   L1_wait_ms = dFETCH_MB * 0.156.  Saturates at 2.6ms.
  if (!IS_L1 && bid == 0) {
    if (tid == 0) {
      // Safety: wait until ALL L1 blocks fully done (their gate1 chain also
      // proves all L0 done) so the scribbled h0 slots can never be read.
      waitCtr8(sync + (2 * 8) * 32, 8u * (unsigned)(T_ + 1));
      waitCtr8(sync + (3 * 8) * 32, 8u * (unsigned)(T_ + 1));
      ((long long*)zbAll)[0] = wsum;
    }
    __syncthreads();
    long long nl = ((long long*)zbAll)[0] >> 1;
    if (nl > 200000) nl = 200000;
    char* wb = (char*)(h0hist + BH_);            // slot 1.. : dead post-loop
    for (long long L = tid; L < nl; L += 512)
      __hip_atomic_store((unsigned*)(wb + L * 128), 0x3c003c00u,
                         __ATOMIC_RELAXED, __HIP_MEMORY_SCOPE_AGENT);
  }
  if (IS_L1 && bid == 128) {
    if (tid == 0) ((long long*)zbAll)[0] = wsum;
    __syncthreads();
    long long nl = ((long long*)zbAll)[0] >> 1;
    if (nl > 131000) nl = 131000;
    float s = 0.f;
    for (long long L = tid; L < nl; L += 512)
      s += x32[L * 32];                          // 128B-strided cold reads
    if (s != 0.f || tid == 0)
      storeH2(h1hist, s, s);                     // keep live; slot0 is reset
  }
}

__global__ __launch_bounds__(512, 2)
void lstm_persistent(const f16* __restrict__ x16, const float* __restrict__ x32,
                     const float* __restrict__ W0x, const float* __restrict__ W0h, const float* __restrict__ b0,
                     const float* __restrict__ W1x, const float* __restrict__ W1h, const float* __restrict__ b1,
                     f16* h0hist, f16* h1hist, unsigned* sync,
                     int nslots, int fmask, int lagD)
{
  __shared__ float zbAll[8192];    // 32KB: prologue panels / partial z / final z
  __shared__ float cLDS[512];
  __shared__ float biasLDS[64];
  const int bid = blockIdx.x;
  if (bid >= 128)
    role_main<true >(x16, x32, W1x, W1h, b1, h0hist, h1hist, sync, bid, nslots, fmask, lagD, zbAll, cLDS, biasLDS);
  else
    role_main<false>(x16, x32, W0x, W0h, b0, h0hist, h1hist, sync, bid, nslots, fmask, lagD, zbAll, cLDS, biasLDS);
}

// x fp32 -> f16, once
__global__ void cvt_x(const float* __restrict__ xin, f16* __restrict__ xo)
{
  const int i = (blockIdx.x * 256 + threadIdx.x) * 8;
  const float4 a = *(const float4*)(xin + i);
  const float4 b = *(const float4*)(xin + i + 4);
  f16x8 v;
  v[0] = (f16)a.x; v[1] = (f16)a.y; v[2] = (f16)a.z; v[3] = (f16)a.w;
  v[4] = (f16)b.x; v[5] = (f16)b.y; v[6] = (f16)b.z; v[7] = (f16)b.w;
  *(f16x8*)(xo + i) = v;
}

// out[b][c] = h1_final[b][:] . Wo[:][c] + bo[c]   (fp32 vector math)
__global__ void out_gemm(const f16* __restrict__ h1,
                         const float* __restrict__ Wo, const float* __restrict__ bo,
                         float* __restrict__ out)
{
  __shared__ float ht[1024][8];
  const int tid = threadIdx.x;    // 128 threads
  const int b0r = blockIdx.y * 4;
  for (int i = tid; i < 4096; i += 128) {
    const int rr = i >> 10, k = i & 1023;
    ht[k][rr] = (float)h1[(size_t)(b0r + rr) * H_ + k];
  }
  __syncthreads();
  const int c = blockIdx.x * 125 + tid;
  if (tid < 125) {
    float a0 = 0.f, a1 = 0.f, a2 = 0.f, a3 = 0.f;
#pragma unroll 4
    for (int k = 0; k < 1024; ++k) {
      const float w = Wo[(size_t)k * C_ + c];
      a0 += ht[k][0] * w;
      a1 += ht[k][1] * w;
      a2 += ht[k][2] * w;
      a3 += ht[k][3] * w;
    }
    const float bb = bo[c];
    out[(size_t)(b0r + 0) * C_ + c] = a0 + bb;
    out[(size_t)(b0r + 1) * C_ + c] = a1 + bb;
    out[(size_t)(b0r + 2) * C_ + c] = a2 + bb;
    out[(size_t)(b0r + 3) * C_ + c] = a3 + bb;
  }
}

extern "C" void kernel_launch(void* const* d_in, const int* in_sizes, int n_in,
                              void* d_out, int out_size, void* d_ws, size_t ws_size,
                              hipStream_t stream)
{
  const float* x   = (const float*)d_in[0];
  const float* W0x = (const float*)d_in[1];
  const float* W0h = (const float*)d_in[2];
  const float* b0  = (const float*)d_in[3];
  const float* W1x = (const float*)d_in[4];
  const float* W1h = (const float*)d_in[5];
  const float* b1  = (const float*)d_in[6];
  const float* Wo  = (const float*)d_in[7];
  const float* bo  = (const float*)d_in[8];

  const size_t slotB = (size_t)BH_ * sizeof(f16);              // 128KB per h slot
  const size_t xB    = (size_t)B_ * T_ * I_ * sizeof(f16);     // 8 MB
  const size_t needA = 4096 + (size_t)2 * (T_ + 1) * slotB + xB;
  const size_t needB = 4096 + (size_t)2 * SLOTS_B_ * slotB + xB;
  int nslots, fmask, lagD;
  if (ws_size >= needA)      { nslots = T_ + 1;   fmask = -1; lagD = -1; }
  else if (ws_size >= needB) { nslots = SLOTS_B_; fmask = 15; lagD = 7;  }
  else                       { nslots = 2;        fmask = 0;  lagD = 0;  }
  const size_t histB = (size_t)nslots * slotB;

  unsigned* sync  = (unsigned*)d_ws;                 // arrival counters (4KB)
  f16* h0hist = (f16*)((char*)d_ws + 4096);
  f16* h1hist = (f16*)((char*)h0hist + histB);
  f16* x16    = (f16*)((char*)h1hist + histB);

  hipMemsetAsync(d_ws, 0, 4096 + slotB, stream);
  hipMemsetAsync(h1hist, 0, slotB, stream);

  hipLaunchKernelGGL(cvt_x, dim3((B_ * T_ * I_) / (256 * 8)), dim3(256), 0, stream, x, x16);

  hipLaunchKernelGGL(lstm_persistent, dim3(256), dim3(512), 0, stream,
                     x16, x, W0x, W0h, b0, W1x, W1h, b1, h0hist, h1hist, sync,
                     nslots, fmask, lagD);

  f16* h1fin = h1hist + (size_t)(T_ % nslots) * BH_;
  hipLaunchKernelGGL(out_gemm, dim3(8, 16), dim3(128), 0, stream,
                     h1fin, Wo, bo, (float*)d_out);
}